// Round 11
// baseline (278.515 us; speedup 1.0000x reference)
//
#include <hip/hip_runtime.h>
#include <hip/hip_bf16.h>
#include <math.h>

#define HIDDEN 768
#define NHEADS 12
#define HDIM   64
#define NTOK   1024   // 32*32
#define BATCH  8
#define CIN    256
#define M_ALL  (BATCH * NTOK)   // 8192
#define LSTR   72               // padded stride for QP (register-sourced writes)

typedef __hip_bfloat16 bf16;
typedef short frag8 __attribute__((ext_vector_type(8)));   // 8 bf16 = 4 VGPRs
typedef float f32x4 __attribute__((ext_vector_type(4)));

#define GL2LDS(gp, lp) \
    __builtin_amdgcn_global_load_lds((const __attribute__((address_space(1))) void*)(gp), \
                                     (__attribute__((address_space(3))) void*)(lp), 16, 0, 0)

__device__ __forceinline__ short f2bs(float x){
    union { bf16 h; short s; } u; u.h = __float2bfloat16(x); return u.s;
}
__device__ __forceinline__ float bs2f(short s){
    union { short s; bf16 h; } u; u.s = s; return __bfloat162float(u.h);
}

// Gaussian weight (inference buffers mu=0 sigma=1)
__device__ __forceinline__ float gaussw(float x){
    float x2 = x * x;
    return (__expf(-x2 / 0.50001f) + __expf(-x2 / 2.00001f) + __expf(-x2 / 8.00001f)) * (1.0f / 3.0f);
}

// ------------------------------------------------------------ fused prep kernel
// [0,576):    wq,wk,wv,wo -> wtqkv planes (transpose+cvt, 768x768)
// [576,588):  proj_w straight cast -> wpc [256][768] bf16
// [588,1100): feat [b][256][1024] -> featT [b][1024][256]
// [1100,1116): PEb[n][d] = pe(n,d) + proj_b[d], bf16 [1024][768]
__global__ __launch_bounds__(256) void prep_all(
    const float* __restrict__ wq, const float* __restrict__ wk,
    const float* __restrict__ wv, const float* __restrict__ wo,
    const float* __restrict__ proj_w, const float* __restrict__ proj_b,
    const float* __restrict__ feat,
    short* __restrict__ wtqkv, short* __restrict__ wpc,
    short* __restrict__ featT, short* __restrict__ PEb)
{
    const int blk = blockIdx.x;
    const int tid = threadIdx.x;

    if (blk < 576 || (blk >= 588 && blk < 1100)) {
        __shared__ short t[64][65];
        const float* W; short* WT; int K, N, k0, n0;
        if (blk < 576) {
            int p = blk / 144, rem = blk % 144;
            const float* srcs[4] = {wq, wk, wv, wo};
            W = srcs[p]; WT = wtqkv + (size_t)p * HIDDEN * HIDDEN;
            K = HIDDEN; N = HIDDEN; k0 = (rem / 12) * 64; n0 = (rem % 12) * 64;
        } else {
            int rem = blk - 588;              // 512 = 8 b x 64 (4x16)
            int b = rem / 64; rem %= 64;
            W = feat + (size_t)b * CIN * NTOK; WT = featT + (size_t)b * NTOK * CIN;
            K = CIN; N = NTOK; k0 = (rem / 16) * 64; n0 = (rem % 16) * 64;
        }
        #pragma unroll
        for (int it = 0; it < 16; it++) {
            int e = tid + 256 * it;
            int kk = e / 64, nn = e % 64;
            t[kk][nn] = f2bs(W[(size_t)(k0 + kk) * N + n0 + nn]);
        }
        __syncthreads();
        #pragma unroll
        for (int it = 0; it < 16; it++) {
            int e = tid + 256 * it;
            int nn = e / 64, kk = e % 64;
            WT[(size_t)(n0 + nn) * K + k0 + kk] = t[kk][nn];
        }
    } else if (blk < 588) {
        // straight cast proj_w -> wpc (256*768 = 12 * 16384)
        int base = (blk - 576) * 16384;
        #pragma unroll
        for (int it = 0; it < 64; it++) {
            int e = base + it * 256 + tid;
            wpc[e] = f2bs(proj_w[e]);
        }
    } else {
        // PEb: 16 blocks x 64 rows
        const float kfac = -9.210340371976184f / 768.0f;  // -ln(10000)/HIDDEN
        int n0 = (blk - 1100) * 64;
        for (int it = 0; it < 192; it++) {
            int e = it * 256 + tid;           // 64*768 = 49152 = 192*256
            int r = e / HIDDEN, d = e % HIDDEN;
            int n = n0 + r;
            float ang = (float)n * __expf((float)(2 * (d >> 1)) * kfac);
            float pe  = (d & 1) ? __cosf(ang) : __sinf(ang);
            PEb[(size_t)n * HIDDEN + d] = f2bs(pe + proj_b[d]);
        }
    }
}

// ------------------------------------------------------------ V transpose (bf16 -> bf16)
// v [8192][768] -> vT [B*NH][64][1024]   (vT[bh][d][n])
__global__ __launch_bounds__(256) void transpose_v(
    const short* __restrict__ v, short* __restrict__ vT)
{
    __shared__ short t[64][65];
    const int nt = blockIdx.x;
    const int bh = blockIdx.y;
    const int b = bh / NHEADS, h = bh % NHEADS;
    const int tid = threadIdx.x;
    #pragma unroll
    for (int it = 0; it < 16; it++) {
        int e = tid + 256 * it;
        int rr = e / 64, cc = e % 64;
        t[rr][cc] = v[(size_t)(b * NTOK + nt * 64 + rr) * HIDDEN + h * HDIM + cc];
    }
    __syncthreads();
    #pragma unroll
    for (int it = 0; it < 16; it++) {
        int e = tid + 256 * it;
        int c2 = e / 64, r2 = e % 64;
        vT[((size_t)bh * HDIM + c2) * NTOK + nt * 64 + r2] = t[r2][c2];
    }
}

// ------------------------------------------------------------ generic 128x128 MFMA GEMM (prep GEMMs)
// out[m][col] = sum_k A[z][m][k] * WT[z][col][k]  (+ bias_z[col] if given), bf16 out, ld = ldo
__global__ __launch_bounds__(256) void gemm_pre(
    const short* __restrict__ Abase, long a_z,
    const short* __restrict__ WTbase, long wt_z,
    short* __restrict__ obase, long o_z, int ldo,
    const float* __restrict__ b0, const float* __restrict__ b1, const float* __restrict__ b2,
    int K)
{
    __shared__ short Al[128 * 32];
    __shared__ short Bl[128 * 32];
    const int z = blockIdx.z;
    const short* A  = Abase  + (size_t)z * a_z;
    const short* WT = WTbase + (size_t)z * wt_z;
    short* outv     = obase  + (size_t)z * o_z;
    const float* bias = (z == 0) ? b0 : (z == 1) ? b1 : b2;

    const int tid  = threadIdx.x;
    const int m0   = blockIdx.x * 128;
    const int n0   = blockIdx.y * 128;
    const int lane = tid & 63, wid = tid >> 6;
    const int wm   = (wid >> 1) * 64, wn = (wid & 1) * 64;
    const int l16  = lane & 15, quad = lane >> 4;

    const int sr  = lane >> 2;
    const int ssg = (lane & 3) ^ ((sr >> 1) & 3);
    const int fsw = (l16 >> 1) & 3;

    const f32x4 z4 = {0.f, 0.f, 0.f, 0.f};
    f32x4 acc[4][4];
    #pragma unroll
    for (int i = 0; i < 4; i++)
        #pragma unroll
        for (int j = 0; j < 4; j++) acc[i][j] = z4;

    for (int k0 = 0; k0 < K; k0 += 32) {
        #pragma unroll
        for (int t = 0; t < 2; t++) {
            int rbase = wid * 32 + t * 16;
            int r = rbase + sr;
            GL2LDS(A  + (size_t)(m0 + r) * K + k0 + ssg * 8, &Al[rbase * 32]);
            GL2LDS(WT + (size_t)(n0 + r) * K + k0 + ssg * 8, &Bl[rbase * 32]);
        }
        __syncthreads();
        frag8 af[4], bfr[4];
        #pragma unroll
        for (int i = 0; i < 4; i++)
            af[i]  = *(const frag8*)&Al[(wm + i * 16 + l16) * 32 + ((quad ^ fsw) * 8)];
        #pragma unroll
        for (int j = 0; j < 4; j++)
            bfr[j] = *(const frag8*)&Bl[(wn + j * 16 + l16) * 32 + ((quad ^ fsw) * 8)];
        #pragma unroll
        for (int i = 0; i < 4; i++)
            #pragma unroll
            for (int j = 0; j < 4; j++)
                acc[i][j] = __builtin_amdgcn_mfma_f32_16x16x32_bf16(af[i], bfr[j], acc[i][j], 0, 0, 0);
        __syncthreads();
    }

    #pragma unroll
    for (int i = 0; i < 4; i++) {
        #pragma unroll
        for (int r = 0; r < 4; r++) {
            int m = m0 + wm + i * 16 + quad * 4 + r;
            #pragma unroll
            for (int j = 0; j < 4; j++) {
                int col = n0 + wn + j * 16 + l16;
                float val = acc[i][j][r];
                if (bias) val += bias[col];
                outv[(size_t)m * ldo + col] = f2bs(val);
            }
        }
    }
}

// ------------------------------------------------------------ QKV GEMM (K=256, folded weights)
// q/k/v[z] = featT @ WcT[z]^T + CpeB[z][n_tok]   (CpeB already contains pb/PE/W and bias)
__global__ __launch_bounds__(256) void gemm_qkv(
    const short* __restrict__ A, const short* __restrict__ WcT,
    const short* __restrict__ CpeB,
    short* o0, short* o1, short* o2)
{
    __shared__ short Al[128 * 32];
    __shared__ short Bl[128 * 32];
    const int z = blockIdx.z;
    const short* WT  = WcT  + (size_t)z * HIDDEN * CIN;
    const short* Cpe = CpeB + (size_t)z * NTOK * HIDDEN;
    short* outv      = (z == 0) ? o0 : (z == 1) ? o1 : o2;

    const int tid  = threadIdx.x;
    const int m0   = blockIdx.x * 128;
    const int n0   = blockIdx.y * 128;
    const int lane = tid & 63, wid = tid >> 6;
    const int wm   = (wid >> 1) * 64, wn = (wid & 1) * 64;
    const int l16  = lane & 15, quad = lane >> 4;

    const int sr  = lane >> 2;
    const int ssg = (lane & 3) ^ ((sr >> 1) & 3);
    const int fsw = (l16 >> 1) & 3;

    const f32x4 z4 = {0.f, 0.f, 0.f, 0.f};
    f32x4 acc[4][4];
    #pragma unroll
    for (int i = 0; i < 4; i++)
        #pragma unroll
        for (int j = 0; j < 4; j++) acc[i][j] = z4;

    for (int k0 = 0; k0 < CIN; k0 += 32) {
        #pragma unroll
        for (int t = 0; t < 2; t++) {
            int rbase = wid * 32 + t * 16;
            int r = rbase + sr;
            GL2LDS(A  + (size_t)(m0 + r) * CIN + k0 + ssg * 8, &Al[rbase * 32]);
            GL2LDS(WT + (size_t)(n0 + r) * CIN + k0 + ssg * 8, &Bl[rbase * 32]);
        }
        __syncthreads();
        frag8 af[4], bfr[4];
        #pragma unroll
        for (int i = 0; i < 4; i++)
            af[i]  = *(const frag8*)&Al[(wm + i * 16 + l16) * 32 + ((quad ^ fsw) * 8)];
        #pragma unroll
        for (int j = 0; j < 4; j++)
            bfr[j] = *(const frag8*)&Bl[(wn + j * 16 + l16) * 32 + ((quad ^ fsw) * 8)];
        #pragma unroll
        for (int i = 0; i < 4; i++)
            #pragma unroll
            for (int j = 0; j < 4; j++)
                acc[i][j] = __builtin_amdgcn_mfma_f32_16x16x32_bf16(af[i], bfr[j], acc[i][j], 0, 0, 0);
        __syncthreads();
    }

    #pragma unroll
    for (int i = 0; i < 4; i++) {
        #pragma unroll
        for (int r = 0; r < 4; r++) {
            int m = m0 + wm + i * 16 + quad * 4 + r;
            int nt = m & (NTOK - 1);
            #pragma unroll
            for (int j = 0; j < 4; j++) {
                int col = n0 + wn + j * 16 + l16;
                outv[(size_t)m * HIDDEN + col] =
                    f2bs(acc[i][j][r] + bs2f(Cpe[(size_t)nt * HIDDEN + col]));
            }
        }
    }
}

// ------------------------------------------------------------ MFMA GEMM 64x128 (final projection)
__global__ __launch_bounds__(256) void gemm_final(
    const short* __restrict__ A, const short* __restrict__ WT,
    const float* __restrict__ bias, float* __restrict__ outv, int K)
{
    __shared__ short Al[64 * 32];
    __shared__ short Bl[128 * 32];
    const int tid  = threadIdx.x;
    const int m0   = blockIdx.x * 64;
    const int n0   = blockIdx.y * 128;
    const int lane = tid & 63, wid = tid >> 6;
    const int wn   = wid * 32;
    const int l16  = lane & 15, quad = lane >> 4;

    const int sr  = lane >> 2;
    const int ssg = (lane & 3) ^ ((sr >> 1) & 3);
    const int fsw = (l16 >> 1) & 3;

    const f32x4 z4 = {0.f, 0.f, 0.f, 0.f};
    f32x4 acc[4][2];
    #pragma unroll
    for (int i = 0; i < 4; i++)
        #pragma unroll
        for (int j = 0; j < 2; j++) acc[i][j] = z4;

    for (int k0 = 0; k0 < K; k0 += 32) {
        GL2LDS(A + (size_t)(m0 + wid * 16 + sr) * K + k0 + ssg * 8, &Al[(wid * 16) * 32]);
        #pragma unroll
        for (int t = 0; t < 2; t++) {
            int rbase = wid * 32 + t * 16;
            GL2LDS(WT + (size_t)(n0 + rbase + sr) * K + k0 + ssg * 8, &Bl[rbase * 32]);
        }
        __syncthreads();
        frag8 af[4], bfr[2];
        #pragma unroll
        for (int i = 0; i < 4; i++)
            af[i]  = *(const frag8*)&Al[(i * 16 + l16) * 32 + ((quad ^ fsw) * 8)];
        #pragma unroll
        for (int j = 0; j < 2; j++)
            bfr[j] = *(const frag8*)&Bl[(wn + j * 16 + l16) * 32 + ((quad ^ fsw) * 8)];
        #pragma unroll
        for (int i = 0; i < 4; i++)
            #pragma unroll
            for (int j = 0; j < 2; j++)
                acc[i][j] = __builtin_amdgcn_mfma_f32_16x16x32_bf16(af[i], bfr[j], acc[i][j], 0, 0, 0);
        __syncthreads();
    }

    #pragma unroll
    for (int i = 0; i < 4; i++) {
        #pragma unroll
        for (int r = 0; r < 4; r++) {
            int m = m0 + i * 16 + quad * 4 + r;
            #pragma unroll
            for (int j = 0; j < 2; j++) {
                int col = n0 + wn + j * 16 + l16;
                outv[(size_t)m * HIDDEN + col] = acc[i][j][r] + bias[col];
            }
        }
    }
}

// ------------------------------------------------------------- MFMA flash attention (unchanged from r10)
__global__ __launch_bounds__(256, 3) void attn_mfma(
    const short* __restrict__ q, const short* __restrict__ k, const short* __restrict__ vT,
    const float* __restrict__ I, const float* __restrict__ lam_p, short* __restrict__ out)
{
    __shared__ short QP[128 * LSTR];
    __shared__ short Ks[64 * 64];
    __shared__ short Vt[64 * 64];
    __shared__ float gL[NTOK];

    const int tid  = threadIdx.x;
    const int lin  = blockIdx.x;
    const int xcd  = lin & 7, slot = lin >> 3;
    const int b    = xcd;
    const int h    = slot >> 3;
    const int qt   = slot & 7;
    const float L2E  = 1.4426950408889634f;
    const float lam2 = lam_p[0] * L2E;
    const float scl  = 0.125f * L2E;
    const int lane = tid & 63, wave = tid >> 6;
    const int l16  = lane & 15, quad = lane >> 4;

    const int sr   = lane >> 3;
    const int slin = lane & 7;
    const int ssg  = slin ^ sr;
    const int fsw  = l16 & 7;

    for (int i = tid; i < NTOK; i += 256) gL[i] = gaussw(I[b * NTOK + i]);

    #pragma unroll
    for (int it = 0; it < 4; it++) {
        int e = tid + 256 * it;
        int r = e >> 3, seg = e & 7;
        *(frag8*)&QP[r * LSTR + seg * 8] =
            *(const frag8*)&q[(size_t)(b * NTOK + qt * 128 + r) * HIDDEN + h * HDIM + seg * 8];
    }
    __syncthreads();

    frag8 aq[2][2];
    #pragma unroll
    for (int half = 0; half < 2; half++) {
        aq[half][0] = *(const frag8*)&QP[(wave * 32 + half * 16 + l16) * LSTR + quad * 8];
        aq[half][1] = *(const frag8*)&QP[(wave * 32 + half * 16 + l16) * LSTR + 32 + quad * 8];
    }
    float gi[2][4];
    #pragma unroll
    for (int half = 0; half < 2; half++)
        #pragma unroll
        for (int r = 0; r < 4; r++)
            gi[half][r] = gL[qt * 128 + wave * 32 + half * 16 + quad * 4 + r];

    const f32x4 z4 = {0.f, 0.f, 0.f, 0.f};
    f32x4 o_acc[2][4];
    #pragma unroll
    for (int half = 0; half < 2; half++)
        #pragma unroll
        for (int d = 0; d < 4; d++) o_acc[half][d] = z4;
    float l_run[2][4] = {};

    const size_t kb  = (size_t)b * NTOK * HIDDEN + h * HDIM;
    const size_t vtb = (size_t)(b * NHEADS + h) * HDIM * NTOK;

    for (int jt = 0; jt < 16; jt++) {
        __syncthreads();
        #pragma unroll
        for (int t = 0; t < 2; t++) {
            int rbase = wave * 16 + t * 8;
            int r = rbase + sr;
            GL2LDS(k  + kb  + (size_t)(jt * 64 + r) * HIDDEN + ssg * 8, &Ks[rbase * 64]);
            GL2LDS(vT + vtb + (size_t)r * NTOK + jt * 64 + ssg * 8,     &Vt[rbase * 64]);
        }
        __syncthreads();

        float p[2][4][4];
        #pragma unroll
        for (int t4 = 0; t4 < 4; t4++) {
            frag8 bk0 = *(const frag8*)&Ks[(t4 * 16 + l16) * 64 + ((quad ^ fsw) * 8)];
            frag8 bk1 = *(const frag8*)&Ks[(t4 * 16 + l16) * 64 + (((quad + 4) ^ fsw) * 8)];
            #pragma unroll
            for (int half = 0; half < 2; half++) {
                f32x4 a = z4;
                a = __builtin_amdgcn_mfma_f32_16x16x32_bf16(aq[half][0], bk0, a, 0, 0, 0);
                a = __builtin_amdgcn_mfma_f32_16x16x32_bf16(aq[half][1], bk1, a, 0, 0, 0);
                #pragma unroll
                for (int r = 0; r < 4; r++) p[half][t4][r] = a[r];
            }
        }

        float gjs[4];
        #pragma unroll
        for (int t4 = 0; t4 < 4; t4++) gjs[t4] = lam2 * gL[jt * 64 + t4 * 16 + l16];

        #pragma unroll
        for (int half = 0; half < 2; half++)
            #pragma unroll
            for (int t4 = 0; t4 < 4; t4++)
                #pragma unroll
                for (int r = 0; r < 4; r++) {
                    float e = exp2f(p[half][t4][r] * scl + gi[half][r] * gjs[t4]);
                    l_run[half][r] += e;
                    QP[(wave * 32 + half * 16 + quad * 4 + r) * LSTR + t4 * 16 + l16] = f2bs(e);
                }

        frag8 ap[2][2];
        #pragma unroll
        for (int half = 0; half < 2; half++) {
            ap[half][0] = *(const frag8*)&QP[(wave * 32 + half * 16 + l16) * LSTR + quad * 8];
            ap[half][1] = *(const frag8*)&QP[(wave * 32 + half * 16 + l16) * LSTR + 32 + quad * 8];
        }
        #pragma unroll
        for (int d = 0; d < 4; d++) {
            frag8 bv0 = *(const frag8*)&Vt[(d * 16 + l16) * 64 + ((quad ^ fsw) * 8)];
            frag8 bv1 = *(const frag8*)&Vt[(d * 16 + l16) * 64 + (((quad + 4) ^ fsw) * 8)];
            #pragma unroll
            for (int half = 0; half < 2; half++) {
                o_acc[half][d] = __builtin_amdgcn_mfma_f32_16x16x32_bf16(ap[half][0], bv0, o_acc[half][d], 0, 0, 0);
                o_acc[half][d] = __builtin_amdgcn_mfma_f32_16x16x32_bf16(ap[half][1], bv1, o_acc[half][d], 0, 0, 0);
            }
        }
    }

    #pragma unroll
    for (int half = 0; half < 2; half++)
        #pragma unroll
        for (int r = 0; r < 4; r++) {
            float l = l_run[half][r];
            #pragma unroll
            for (int off = 1; off < 16; off <<= 1) l += __shfl_xor(l, off);
            float inv_l = 1.0f / l;
            int row = qt * 128 + wave * 32 + half * 16 + quad * 4 + r;
            #pragma unroll
            for (int d = 0; d < 4; d++)
                out[(size_t)(b * NTOK + row) * HIDDEN + h * HDIM + d * 16 + l16]
                    = f2bs(o_acc[half][d][r] * inv_l);
        }
}

// ---------------------------------------------------------------- launch
extern "C" void kernel_launch(void* const* d_in, const int* in_sizes, int n_in,
                              void* d_out, int out_size, void* d_ws, size_t ws_size,
                              hipStream_t stream)
{
    const float* feat   = (const float*)d_in[0];
    const float* I      = (const float*)d_in[1];
    const float* proj_w = (const float*)d_in[2];
    const float* proj_b = (const float*)d_in[3];
    const float* wq     = (const float*)d_in[4];
    const float* bq     = (const float*)d_in[5];
    const float* wk     = (const float*)d_in[6];
    const float* bk     = (const float*)d_in[7];
    const float* wv     = (const float*)d_in[8];
    const float* bv     = (const float*)d_in[9];
    const float* wo     = (const float*)d_in[10];
    const float* bo     = (const float*)d_in[11];
    const float* lam    = (const float*)d_in[12];
    float* out = (float*)d_out;

    // ws (shorts), ~30 MB:
    // [wtqkv 4 planes][ region2: phase-A scratch then vT ][ qbuf ]
    short* wtqkv = (short*)d_ws;                                   // 4*589824
    short* wto   = wtqkv + (size_t)3 * HIDDEN * HIDDEN;
    short* reg2  = wtqkv + (size_t)4 * HIDDEN * HIDDEN;
    //   phase A inside reg2 (total 6,029,312 < 6,291,456):
    short* wpc   = reg2;                                            // 196,608
    short* PEb   = wpc  + (size_t)CIN * HIDDEN;                     // 786,432
    short* featT = PEb  + (size_t)NTOK * HIDDEN;                    // 2,097,152
    short* WcT   = featT + (size_t)M_ALL * CIN;                     // 589,824
    short* CpeB  = WcT  + (size_t)3 * HIDDEN * CIN;                 // 2,359,296
    //   phase B: vT aliases reg2 (all phase-A dead by then)
    short* vTb   = reg2;                                            // 6,291,456
    short* qbuf  = reg2 + (size_t)M_ALL * HIDDEN;                   // 6,291,456
    short* kbuf  = (short*)d_out;                                   // k,v in d_out
    short* vbuf  = kbuf + (size_t)M_ALL * HIDDEN;

    // 1. prep: weight transposes, wpc cast, featT, PEb
    prep_all<<<1116, 256, 0, stream>>>(wq, wk, wv, wo, proj_w, proj_b, feat,
                                       wtqkv, wpc, featT, PEb);
    // 2. WcT[z] = (Wp @ Wz)^T : A=wtqkv planes, WT=wpc, K=768, out [768][256]
    gemm_pre<<<dim3(6, 2, 3), 256, 0, stream>>>(wtqkv, (long)HIDDEN * HIDDEN,
                                                wpc, 0,
                                                WcT, (long)HIDDEN * CIN, CIN,
                                                nullptr, nullptr, nullptr, HIDDEN);
    // 3. CpeB[z] = PEb @ Wz + b_z : A=PEb, WT=wtqkv planes, K=768, out [1024][768]
    gemm_pre<<<dim3(8, 6, 3), 256, 0, stream>>>(PEb, 0,
                                                wtqkv, (long)HIDDEN * HIDDEN,
                                                CpeB, (long)NTOK * HIDDEN, HIDDEN,
                                                bq, bk, bv, HIDDEN);
    // 4. QKV at K=256: q/k/v = featT @ WcT[z] + CpeB[z][n]
    gemm_qkv<<<dim3(64, 6, 3), 256, 0, stream>>>(featT, WcT, CpeB, qbuf, kbuf, vbuf);
    // 5. V transpose (phase-A scratch dead -> vT lands on reg2)
    transpose_v<<<dim3(16, 96), 256, 0, stream>>>(vbuf, vTb);
    // 6. attention (out in-place into qbuf)
    attn_mfma<<<768, 256, 0, stream>>>(qbuf, kbuf, vTb, I, lam, qbuf);
    // 7. final projection (f32 out)
    gemm_final<<<dim3(128, 6), 256, 0, stream>>>(qbuf, wto, bo, out, HIDDEN);
}

// Round 12
// 246.904 us; speedup vs baseline: 1.1280x; 1.1280x over previous
//
#include <hip/hip_runtime.h>
#include <hip/hip_bf16.h>
#include <math.h>

#define HIDDEN 768
#define NHEADS 12
#define HDIM   64
#define NTOK   1024   // 32*32
#define BATCH  8
#define CIN    256
#define M_ALL  (BATCH * NTOK)   // 8192
#define LSTR   72               // padded stride for QP (register-sourced writes)

typedef __hip_bfloat16 bf16;
typedef short frag8 __attribute__((ext_vector_type(8)));   // 8 bf16 = 4 VGPRs
typedef float f32x4 __attribute__((ext_vector_type(4)));

#define GL2LDS(gp, lp) \
    __builtin_amdgcn_global_load_lds((const __attribute__((address_space(1))) void*)(gp), \
                                     (__attribute__((address_space(3))) void*)(lp), 16, 0, 0)

__device__ __forceinline__ short f2bs(float x){
    union { bf16 h; short s; } u; u.h = __float2bfloat16(x); return u.s;
}

// Gaussian weight (inference buffers mu=0 sigma=1)
__device__ __forceinline__ float gaussw(float x){
    float x2 = x * x;
    return (__expf(-x2 / 0.50001f) + __expf(-x2 / 2.00001f) + __expf(-x2 / 8.00001f)) * (1.0f / 3.0f);
}

// ------------------------------------------------------------ fused prep kernel (r10 version)
// [0,576):    wq,wk,wv,wo -> wtqkv planes (transpose+cvt, 768x768)
// [576,624):  proj_w transpose (256x768 -> wtp[768][256])
// [624,1136): feat [b][256][1024] -> featT [b][1024][256]
__global__ __launch_bounds__(256) void prep_all(
    const float* __restrict__ wq, const float* __restrict__ wk,
    const float* __restrict__ wv, const float* __restrict__ wo,
    const float* __restrict__ proj_w, const float* __restrict__ feat,
    short* __restrict__ wtqkv, short* __restrict__ wtp, short* __restrict__ featT)
{
    __shared__ short t[64][65];
    const int blk = blockIdx.x;
    const float* W; short* WT; int K, N, k0, n0;
    if (blk < 576) {
        int p = blk / 144, rem = blk % 144;
        const float* srcs[4] = {wq, wk, wv, wo};
        W = srcs[p]; WT = wtqkv + (size_t)p * HIDDEN * HIDDEN;
        K = HIDDEN; N = HIDDEN; k0 = (rem / 12) * 64; n0 = (rem % 12) * 64;
    } else if (blk < 624) {
        int rem = blk - 576;
        W = proj_w; WT = wtp;
        K = CIN; N = HIDDEN; k0 = (rem / 12) * 64; n0 = (rem % 12) * 64;
    } else {
        int rem = blk - 624;              // 512 = 8 b x 64 (4x16)
        int b = rem / 64; rem %= 64;
        W = feat + (size_t)b * CIN * NTOK; WT = featT + (size_t)b * NTOK * CIN;
        K = CIN; N = NTOK; k0 = (rem / 16) * 64; n0 = (rem % 16) * 64;
    }
    const int tid = threadIdx.x;
    #pragma unroll
    for (int it = 0; it < 16; it++) {
        int e = tid + 256 * it;
        int kk = e / 64, nn = e % 64;
        t[kk][nn] = f2bs(W[(size_t)(k0 + kk) * N + n0 + nn]);
    }
    __syncthreads();
    #pragma unroll
    for (int it = 0; it < 16; it++) {
        int e = tid + 256 * it;
        int nn = e / 64, kk = e % 64;
        WT[(size_t)(n0 + nn) * K + k0 + kk] = t[kk][nn];
    }
}

// ------------------------------------------------------------ MFMA GEMM 128x128 (QKV)
// A bf16 [M_ALL][K]; WT bf16 [768][K]; bias f32 [768].
// z=0 -> q (rows), z=1 -> k (rows), z=2 -> V written TRANSPOSED into vT[bh][d][n]
__global__ __launch_bounds__(256) void gemm_qkv(
    const short* __restrict__ A, const short* __restrict__ WT0, long wt_z,
    const float* __restrict__ b0, const float* __restrict__ b1, const float* __restrict__ b2,
    short* o0, short* o1, short* vT, int K)
{
    __shared__ short pool[128 * 136];    // union: staging (Al 4096 + Bl 4096) / v-transpose tile
    short* Al = pool;
    short* Bl = pool + 128 * 32;
    const int z = blockIdx.z;
    const short* WT  = WT0 + (size_t)z * wt_z;
    const float* bias = (z == 0) ? b0 : (z == 1) ? b1 : b2;

    const int tid  = threadIdx.x;
    const int m0   = blockIdx.x * 128;
    const int n0   = blockIdx.y * 128;
    const int lane = tid & 63, wid = tid >> 6;
    const int wm   = (wid >> 1) * 64, wn = (wid & 1) * 64;
    const int l16  = lane & 15, quad = lane >> 4;

    const int sr  = lane >> 2;
    const int ssg = (lane & 3) ^ ((sr >> 1) & 3);
    const int fsw = (l16 >> 1) & 3;

    const f32x4 z4 = {0.f, 0.f, 0.f, 0.f};
    f32x4 acc[4][4];
    #pragma unroll
    for (int i = 0; i < 4; i++)
        #pragma unroll
        for (int j = 0; j < 4; j++) acc[i][j] = z4;

    for (int k0 = 0; k0 < K; k0 += 32) {
        #pragma unroll
        for (int t = 0; t < 2; t++) {
            int rbase = wid * 32 + t * 16;
            int r = rbase + sr;
            GL2LDS(A  + (size_t)(m0 + r) * K + k0 + ssg * 8, &Al[rbase * 32]);
            GL2LDS(WT + (size_t)(n0 + r) * K + k0 + ssg * 8, &Bl[rbase * 32]);
        }
        __syncthreads();
        frag8 af[4], bfr[4];
        #pragma unroll
        for (int i = 0; i < 4; i++)
            af[i]  = *(const frag8*)&Al[(wm + i * 16 + l16) * 32 + ((quad ^ fsw) * 8)];
        #pragma unroll
        for (int j = 0; j < 4; j++)
            bfr[j] = *(const frag8*)&Bl[(wn + j * 16 + l16) * 32 + ((quad ^ fsw) * 8)];
        #pragma unroll
        for (int i = 0; i < 4; i++)
            #pragma unroll
            for (int j = 0; j < 4; j++)
                acc[i][j] = __builtin_amdgcn_mfma_f32_16x16x32_bf16(af[i], bfr[j], acc[i][j], 0, 0, 0);
        __syncthreads();
    }

    if (z != 2) {
        short* outv = (z == 0) ? o0 : o1;
        #pragma unroll
        for (int i = 0; i < 4; i++)
            #pragma unroll
            for (int r = 0; r < 4; r++) {
                int m = m0 + wm + i * 16 + quad * 4 + r;
                #pragma unroll
                for (int j = 0; j < 4; j++) {
                    int col = n0 + wn + j * 16 + l16;
                    outv[(size_t)m * HIDDEN + col] = f2bs(acc[i][j][r] + bias[col]);
                }
            }
    } else {
        // V: transpose 128x128 tile via LDS, store coalesced into vT[bh][d][n]
        // (staging buffers dead after final k-loop barrier)
        #pragma unroll
        for (int i = 0; i < 4; i++)
            #pragma unroll
            for (int r = 0; r < 4; r++) {
                int mloc = wm + i * 16 + quad * 4 + r;
                #pragma unroll
                for (int j = 0; j < 4; j++) {
                    int cc = wn + j * 16 + l16;
                    pool[cc * 136 + mloc] = f2bs(acc[i][j][r] + bias[n0 + cc]);
                }
            }
        __syncthreads();
        const int bb   = m0 >> 10;          // batch (128 | 1024)
        const int nloc = m0 & 1023;
        #pragma unroll
        for (int it = 0; it < 8; it++) {
            int cc  = (tid >> 4) + it * 16;  // 0..127 (local col = d)
            int seg = tid & 15;
            int gcol = n0 + cc;
            short* dst = vT + ((size_t)(bb * NHEADS + (gcol >> 6)) * HDIM + (gcol & 63)) * NTOK
                            + nloc + seg * 8;
            *(frag8*)dst = *(const frag8*)&pool[cc * 136 + seg * 8];
        }
    }
}

// ------------------------------------------------------------ MFMA GEMM 64x128 (tokens / final)
// MODE 1: out bf16 = acc+bias+PE; MODE 2: out f32 = acc+bias
template<int MODE>
__global__ __launch_bounds__(256) void gemm_mfma64(
    const short* __restrict__ A, const short* __restrict__ WT,
    const float* __restrict__ bias, void* outv, int K)
{
    __shared__ short Al[64 * 32];
    __shared__ short Bl[128 * 32];
    const int tid  = threadIdx.x;
    const int m0   = blockIdx.x * 64;
    const int n0   = blockIdx.y * 128;
    const int lane = tid & 63, wid = tid >> 6;
    const int wn   = wid * 32;
    const int l16  = lane & 15, quad = lane >> 4;

    const int sr  = lane >> 2;
    const int ssg = (lane & 3) ^ ((sr >> 1) & 3);
    const int fsw = (l16 >> 1) & 3;

    const f32x4 z4 = {0.f, 0.f, 0.f, 0.f};
    f32x4 acc[4][2];
    #pragma unroll
    for (int i = 0; i < 4; i++)
        #pragma unroll
        for (int j = 0; j < 2; j++) acc[i][j] = z4;

    for (int k0 = 0; k0 < K; k0 += 32) {
        GL2LDS(A + (size_t)(m0 + wid * 16 + sr) * K + k0 + ssg * 8, &Al[(wid * 16) * 32]);
        #pragma unroll
        for (int t = 0; t < 2; t++) {
            int rbase = wid * 32 + t * 16;
            GL2LDS(WT + (size_t)(n0 + rbase + sr) * K + k0 + ssg * 8, &Bl[rbase * 32]);
        }
        __syncthreads();
        frag8 af[4], bfr[2];
        #pragma unroll
        for (int i = 0; i < 4; i++)
            af[i]  = *(const frag8*)&Al[(i * 16 + l16) * 32 + ((quad ^ fsw) * 8)];
        #pragma unroll
        for (int j = 0; j < 2; j++)
            bfr[j] = *(const frag8*)&Bl[(wn + j * 16 + l16) * 32 + ((quad ^ fsw) * 8)];
        #pragma unroll
        for (int i = 0; i < 4; i++)
            #pragma unroll
            for (int j = 0; j < 2; j++)
                acc[i][j] = __builtin_amdgcn_mfma_f32_16x16x32_bf16(af[i], bfr[j], acc[i][j], 0, 0, 0);
        __syncthreads();
    }

    const float kfac = -9.210340371976184f / 768.0f;  // -ln(10000)/HIDDEN
    #pragma unroll
    for (int i = 0; i < 4; i++) {
        #pragma unroll
        for (int r = 0; r < 4; r++) {
            int m = m0 + i * 16 + quad * 4 + r;
            #pragma unroll
            for (int j = 0; j < 2; j++) {
                int col = n0 + wn + j * 16 + l16;
                float val = acc[i][j][r] + bias[col];
                if (MODE == 1) {
                    int n_tok = m & (NTOK - 1);
                    float ang = (float)n_tok * expf((float)(2 * (col >> 1)) * kfac);
                    val += (col & 1) ? cosf(ang) : sinf(ang);
                }
                if (MODE == 2) ((float*)outv)[(size_t)m * HIDDEN + col] = val;
                else           ((short*)outv)[(size_t)m * HIDDEN + col] = f2bs(val);
            }
        }
    }
}

// ------------------------------------------------------------- MFMA flash attention
// 64-row q-tiles -> 1536 blocks (5 blocks/CU by LDS), XCD-pinned per batch.
// No-max softmax (scores bounded); Ks/Vt GL2LDS-staged, XOR-swizzled.
__global__ __launch_bounds__(256) void attn_mfma(
    const short* __restrict__ q, const short* __restrict__ k, const short* __restrict__ vT,
    const float* __restrict__ I, const float* __restrict__ lam_p, short* __restrict__ out)
{
    __shared__ short QP[64 * LSTR];    // Q staging (then P), padded
    __shared__ short Ks[64 * 64];
    __shared__ short Vt[64 * 64];
    __shared__ float gL[NTOK];

    const int tid  = threadIdx.x;
    const int lin  = blockIdx.x;
    const int xcd  = lin & 7, slot = lin >> 3;     // 1536 = 8 xcd x 192
    const int b    = xcd;
    const int h    = slot >> 4;                     // 0..11
    const int qt   = slot & 15;                     // 0..15 (64-row tiles)
    const float L2E  = 1.4426950408889634f;
    const float lam2 = lam_p[0] * L2E;
    const float scl  = 0.125f * L2E;
    const int lane = tid & 63, wave = tid >> 6;
    const int l16  = lane & 15, quad = lane >> 4;

    const int sr   = lane >> 3;          // staging row within 8-row group
    const int slin = lane & 7;           // dest 16B segment
    const int ssg  = slin ^ sr;          // swizzled source segment
    const int fsw  = l16 & 7;            // frag-read swizzle

    for (int i = tid; i < NTOK; i += 256) gL[i] = gaussw(I[b * NTOK + i]);

    // stage Q tile [64 x 64]
    #pragma unroll
    for (int it = 0; it < 2; it++) {
        int e = tid + 256 * it;
        int r = e >> 3, seg = e & 7;
        *(frag8*)&QP[r * LSTR + seg * 8] =
            *(const frag8*)&q[(size_t)(b * NTOK + qt * 64 + r) * HIDDEN + h * HDIM + seg * 8];
    }
    __syncthreads();

    // hoist Q A-frags (wave rows = wave*16 + l16)
    frag8 aq0 = *(const frag8*)&QP[(wave * 16 + l16) * LSTR + quad * 8];
    frag8 aq1 = *(const frag8*)&QP[(wave * 16 + l16) * LSTR + 32 + quad * 8];
    float gi[4];
    #pragma unroll
    for (int r = 0; r < 4; r++) gi[r] = gL[qt * 64 + wave * 16 + quad * 4 + r];

    const f32x4 z4 = {0.f, 0.f, 0.f, 0.f};
    f32x4 o_acc[4];
    #pragma unroll
    for (int d = 0; d < 4; d++) o_acc[d] = z4;
    float l_run[4] = {};

    const size_t kb  = (size_t)b * NTOK * HIDDEN + h * HDIM;
    const size_t vtb = (size_t)(b * NHEADS + h) * HDIM * NTOK;

    for (int jt = 0; jt < 16; jt++) {
        __syncthreads();    // prev iteration's LDS reads complete
        #pragma unroll
        for (int t = 0; t < 2; t++) {
            int rbase = wave * 16 + t * 8;
            int r = rbase + sr;
            GL2LDS(k  + kb  + (size_t)(jt * 64 + r) * HIDDEN + ssg * 8, &Ks[rbase * 64]);
            GL2LDS(vT + vtb + (size_t)r * NTOK + jt * 64 + ssg * 8,     &Vt[rbase * 64]);
        }
        __syncthreads();    // tiles ready

        // S = Q.K^T : wave's 16 rows x 64 keys
        float p[4][4];
        #pragma unroll
        for (int t4 = 0; t4 < 4; t4++) {
            frag8 bk0 = *(const frag8*)&Ks[(t4 * 16 + l16) * 64 + ((quad ^ fsw) * 8)];
            frag8 bk1 = *(const frag8*)&Ks[(t4 * 16 + l16) * 64 + (((quad + 4) ^ fsw) * 8)];
            f32x4 a = z4;
            a = __builtin_amdgcn_mfma_f32_16x16x32_bf16(aq0, bk0, a, 0, 0, 0);
            a = __builtin_amdgcn_mfma_f32_16x16x32_bf16(aq1, bk1, a, 0, 0, 0);
            #pragma unroll
            for (int r = 0; r < 4; r++) p[t4][r] = a[r];
        }

        // fixed-reference exp in log2 domain
        float gjs[4];
        #pragma unroll
        for (int t4 = 0; t4 < 4; t4++) gjs[t4] = lam2 * gL[jt * 64 + t4 * 16 + l16];

        #pragma unroll
        for (int t4 = 0; t4 < 4; t4++)
            #pragma unroll
            for (int r = 0; r < 4; r++) {
                float e = exp2f(p[t4][r] * scl + gi[r] * gjs[t4]);
                l_run[r] += e;
                QP[(wave * 16 + quad * 4 + r) * LSTR + t4 * 16 + l16] = f2bs(e);
            }

        // O += P.V  (P rows wave-private; Vt guarded by post-stage barrier)
        frag8 ap0 = *(const frag8*)&QP[(wave * 16 + l16) * LSTR + quad * 8];
        frag8 ap1 = *(const frag8*)&QP[(wave * 16 + l16) * LSTR + 32 + quad * 8];
        #pragma unroll
        for (int d = 0; d < 4; d++) {
            frag8 bv0 = *(const frag8*)&Vt[(d * 16 + l16) * 64 + ((quad ^ fsw) * 8)];
            frag8 bv1 = *(const frag8*)&Vt[(d * 16 + l16) * 64 + (((quad + 4) ^ fsw) * 8)];
            o_acc[d] = __builtin_amdgcn_mfma_f32_16x16x32_bf16(ap0, bv0, o_acc[d], 0, 0, 0);
            o_acc[d] = __builtin_amdgcn_mfma_f32_16x16x32_bf16(ap1, bv1, o_acc[d], 0, 0, 0);
        }
    }

    // epilogue: reduce l across the 16 lanes sharing each row, normalize, store
    #pragma unroll
    for (int r = 0; r < 4; r++) {
        float l = l_run[r];
        #pragma unroll
        for (int off = 1; off < 16; off <<= 1) l += __shfl_xor(l, off);
        float inv_l = 1.0f / l;
        int row = qt * 64 + wave * 16 + quad * 4 + r;
        #pragma unroll
        for (int d = 0; d < 4; d++)
            out[(size_t)(b * NTOK + row) * HIDDEN + h * HDIM + d * 16 + l16]
                = f2bs(o_acc[d][r] * inv_l);
    }
}

// ---------------------------------------------------------------- launch
extern "C" void kernel_launch(void* const* d_in, const int* in_sizes, int n_in,
                              void* d_out, int out_size, void* d_ws, size_t ws_size,
                              hipStream_t stream)
{
    const float* feat   = (const float*)d_in[0];
    const float* I      = (const float*)d_in[1];
    const float* proj_w = (const float*)d_in[2];
    const float* proj_b = (const float*)d_in[3];
    const float* wq     = (const float*)d_in[4];
    const float* bq     = (const float*)d_in[5];
    const float* wk     = (const float*)d_in[6];
    const float* bk     = (const float*)d_in[7];
    const float* wv     = (const float*)d_in[8];
    const float* bv     = (const float*)d_in[9];
    const float* wo     = (const float*)d_in[10];
    const float* bo     = (const float*)d_in[11];
    const float* lam    = (const float*)d_in[12];
    float* out = (float*)d_out;

    // ws (shorts), ~30.3 MB (same as r10):
    short* wtqkv = (short*)d_ws;                          // 4 planes (wq,wk,wv,wo)
    short* wto   = wtqkv + (size_t)3 * HIDDEN * HIDDEN;
    short* wtp   = wtqkv + (size_t)4 * HIDDEN * HIDDEN;
    short* tokens= wtp   + (size_t)HIDDEN * CIN;
    short* qbuf  = tokens+ (size_t)M_ALL * HIDDEN;
    short* featT = qbuf;                                  // featT dead after tokens GEMM
    // d_out: kbuf | vT (both dead before final GEMM writes d_out)
    short* kbuf  = (short*)d_out;
    short* vTb   = kbuf + (size_t)M_ALL * HIDDEN;

    // 1. prep: weight transposes + feat transpose
    prep_all<<<1136, 256, 0, stream>>>(wq, wk, wv, wo, proj_w, feat, wtqkv, wtp, featT);
    // 2. tokens = featT @ proj_w + b + PE   (64x128 tiles, 768 blocks)
    gemm_mfma64<1><<<dim3(128, 6), 256, 0, stream>>>(featT, wtp, proj_b, tokens, CIN);
    // 3. fused QKV; V written transposed into vT (d_out second half)
    gemm_qkv<<<dim3(64, 6, 3), 256, 0, stream>>>(tokens, wtqkv, (long)HIDDEN * HIDDEN,
                                                 bq, bk, bv,
                                                 qbuf, kbuf, vTb, HIDDEN);
    // 4. attention (64-row q-tiles, 1536 blocks, out in-place into qbuf)
    attn_mfma<<<1536, 256, 0, stream>>>(qbuf, kbuf, vTb, I, lam, qbuf);
    // 5. final projection (f32 out, overwrites kbuf/vT)
    gemm_mfma64<2><<<dim3(128, 6), 256, 0, stream>>>(qbuf, wto, bo, out, HIDDEN);
}